// Round 11
// baseline (2814.643 us; speedup 1.0000x reference)
//
#include <hip/hip_runtime.h>
#include <hip/hip_bf16.h>

using short8 = __attribute__((ext_vector_type(8))) short;
using f32x16 = __attribute__((ext_vector_type(16))) float;
using us4    = __attribute__((ext_vector_type(4))) unsigned short;

#define NHID 15872

__device__ __forceinline__ unsigned short f2bf(float f) {
  unsigned u = __builtin_bit_cast(unsigned, f);
  u += 0x7fff + ((u >> 16) & 1);          // RNE
  return (unsigned short)(u >> 16);
}
__device__ __forceinline__ short f2bf_hw(float f) {
  __hip_bfloat16 h = __float2bfloat16(f);
  return __builtin_bit_cast(short, h);
}
__device__ __forceinline__ float bf2f(unsigned short h) {
  return __builtin_bit_cast(float, ((unsigned)h) << 16);
}

// async global->LDS, 16B/lane. LDS dest = wave-uniform base + lane*16.
__device__ __forceinline__ void gload16(const void* g, void* l) {
  __builtin_amdgcn_global_load_lds(
      (const __attribute__((address_space(1))) unsigned int*)g,
      (__attribute__((address_space(3))) unsigned int*)l, 16, 0, 0);
}

// packed-A layout: (row,k) -> (k>>4)*4096 + (row + 256*((k>>3)&1))*8 + (k&7)
__device__ __forceinline__ size_t pk_idx(int row, int col) {
  return (size_t)(col >> 4) * 4096 +
         (size_t)(row + 256 * ((col >> 3) & 1)) * 8 + (col & 7);
}

// ---------------- kernel 0: x fp32 -> packed bf16 ----------------
__global__ void cvt_x_pack(const float* __restrict__ x, unsigned short* __restrict__ xpk) {
  int g = blockIdx.x * 256 + threadIdx.x;       // 16384 chunks of 8
  int row = g >> 6, k0 = (g & 63) * 8;
  const float* p = x + (size_t)row * 512 + k0;
  float4 a = *reinterpret_cast<const float4*>(p);
  float4 b = *reinterpret_cast<const float4*>(p + 4);
  us4 o0, o1;
  o0[0] = f2bf(a.x); o0[1] = f2bf(a.y); o0[2] = f2bf(a.z); o0[3] = f2bf(a.w);
  o1[0] = f2bf(b.x); o1[1] = f2bf(b.y); o1[2] = f2bf(b.z); o1[3] = f2bf(b.w);
  unsigned short* d = xpk + pk_idx(row, k0);
  *reinterpret_cast<us4*>(d)     = o0;
  *reinterpret_cast<us4*>(d + 4) = o1;
}

// ---------------- main GEMM v11 ----------------
// BM=256, BN=128, BK=32. 512 thr = 8 waves (4m x 2n): wave = 64 rows x 64 cols,
// acc = 4 x f32x16. B-only LDS ring-3 (48 KB) -> 2 WG/CU with DISJOINT B
// (grid 124n x 4k). A global->reg from packed image (L2-hot), reg ping-pong.
// ONE barrier/tile; counted vmcnt(2) keeps B(t+1),B(t+2) in flight.
// OUTMODE: 0 = bias+relu -> packed bf16, 1 = fp32 partials, 2 = rowmajor bf16.

#define WAITV(N) asm volatile("s_waitcnt vmcnt(" #N ")" ::: "memory")

// B tile 32k x 128col fp32: wave w stages rows w*4..w*4+3 (2 instrs x 2 rows)
#define STAGEB(BUF, T) do { \
    gload16(bsrc + (size_t)(T) * 32 * NHID,             &Blds[BUF][(w * 4 + 0) * 128]); \
    gload16(bsrc + ((size_t)(T) * 32 + 2) * NHID,       &Blds[BUF][(w * 4 + 2) * 128]); \
  } while (0)

// A frags for tile T: frag(rb,ks) = 16B at asrc + (T*2+ks)*4096 + rb*256 (shorts)
#define LOADA(R, T) do { \
    const unsigned short* ap_ = asrc + (size_t)(T) * 8192; \
    R[0] = *reinterpret_cast<const short8*>(ap_); \
    R[1] = *reinterpret_cast<const short8*>(ap_ + 4096); \
    R[2] = *reinterpret_cast<const short8*>(ap_ + 256); \
    R[3] = *reinterpret_cast<const short8*>(ap_ + 4096 + 256); \
  } while (0)

#define COMPUTE(AR, BC) do { \
    const float* bb_ = &Blds[BC][0]; \
    _Pragma("unroll") \
    for (int ks_ = 0; ks_ < 2; ++ks_) { \
      short8 bfr_[2]; \
      _Pragma("unroll") \
      for (int nb_ = 0; nb_ < 2; ++nb_) { \
        float tf_[8]; \
        _Pragma("unroll") \
        for (int jj_ = 0; jj_ < 8; ++jj_) \
          tf_[jj_] = bb_[(ks_ * 16 + hi * 8 + jj_) * 128 + wn * 64 + nb_ * 32 + l31]; \
        _Pragma("unroll") \
        for (int jj_ = 0; jj_ < 8; ++jj_) bfr_[nb_][jj_] = f2bf_hw(tf_[jj_]); \
      } \
      acc[0] = __builtin_amdgcn_mfma_f32_32x32x16_bf16(AR[ks_],     bfr_[0], acc[0], 0, 0, 0); \
      acc[1] = __builtin_amdgcn_mfma_f32_32x32x16_bf16(AR[ks_],     bfr_[1], acc[1], 0, 0, 0); \
      acc[2] = __builtin_amdgcn_mfma_f32_32x32x16_bf16(AR[2 + ks_], bfr_[0], acc[2], 0, 0, 0); \
      acc[3] = __builtin_amdgcn_mfma_f32_32x32x16_bf16(AR[2 + ks_], bfr_[1], acc[3], 0, 0, 0); \
    } \
  } while (0)

#define ITER(CUR, NXT) do { \
    if (t + 1 < NT) { WAITV(2); } else { WAITV(0); } \
    __builtin_amdgcn_sched_barrier(0); \
    __builtin_amdgcn_s_barrier(); \
    if (t + 1 < NT) LOADA(NXT, t + 1); \
    if (t + 2 < NT) { int sb_ = bc >= 1 ? bc - 1 : 2; STAGEB(sb_, t + 2); } \
    COMPUTE(CUR, bc); \
    bc = bc == 2 ? 0 : bc + 1; ++t; \
  } while (0)

template<int OUTMODE, bool SWZ>
__global__ __launch_bounds__(512, 4)
void gemm_v11(const unsigned short* __restrict__ Apk, int KC,
              const float* __restrict__ B, const float* __restrict__ bias,
              unsigned short* __restrict__ Cf, float* __restrict__ Cp)
{
  __shared__ float Blds[3][32 * 128];   // 48 KB ring-3

  int nidx, ks0;
  if (SWZ) {
    int b = blockIdx.x;                  // 496 = 62 groups x 8 xcd-slots
    int xcd = b & 7;
    ks0  = xcd >> 1;                     // 2 XCDs per k-chunk (A slice 2MB -> L2)
    nidx = (b >> 3) * 2 + (xcd & 1);     // 0..123
  } else {
    nidx = blockIdx.x; ks0 = blockIdx.y;
  }
  const int n0   = nidx * 128;
  const int k0   = ks0 * KC;
  const int tid  = threadIdx.x;
  const int w    = tid >> 6;
  const int lane = tid & 63;
  const int l31  = lane & 31;
  const int hi   = lane >> 5;
  const int wm   = w >> 1;     // rows wm*64..+63
  const int wn   = w & 1;      // cols wn*64..+63

  f32x16 acc[4] = {};   // [rb*2+nb]

  // B stage src: row = k0 + t*32 + w*4 + {0,2} + (lane>>5), col = n0 + (lane&31)*4
  const float* bsrc = B + (size_t)(k0 + w * 4 + hi) * NHID + n0 + l31 * 4;
  // A frag src (packed): + (t*2+ks)*4096 + rb*256 shorts
  const unsigned short* asrc = Apk + (size_t)(k0 >> 4) * 4096 +
                               (size_t)(wm * 64 + l31 + 256 * hi) * 8;

  const int NT = KC >> 5;   // >= 8 in all uses, even

  short8 rA[4], rB[4];
  STAGEB(0, 0);
  LOADA(rA, 0);
  STAGEB(1, 1);

  int t = 0, bc = 0;
  while (t < NT) {
    ITER(rA, rB);
    if (t == NT) break;
    ITER(rB, rA);
  }

  // epilogue: verified mapping col=base+l31, row=(reg&3)+8*(reg>>2)+4*hi
#pragma unroll
  for (int rb = 0; rb < 2; ++rb) {
#pragma unroll
    for (int nb = 0; nb < 2; ++nb) {
      int col = n0 + wn * 64 + nb * 32 + l31;
      float bv = (OUTMODE != 1) ? bias[col] : 0.f;
#pragma unroll
      for (int reg = 0; reg < 16; ++reg) {
        int row = wm * 64 + rb * 32 + (reg & 3) + 8 * (reg >> 2) + 4 * hi;
        float v = acc[rb * 2 + nb][reg];
        if (OUTMODE == 0) {
          v += bv; v = v > 0.f ? v : 0.f;
          Cf[pk_idx(row, col)] = f2bf(v);
        } else if (OUTMODE == 1) {
          Cp[(size_t)ks0 * 256 * NHID + (size_t)row * NHID + col] = v;
        } else {
          v += bv; v = v > 0.f ? v : 0.f;
          Cf[(size_t)row * NHID + col] = f2bf(v);
        }
      }
    }
  }
}

// ---------------- reduce partials: out = relu(sum + bias) -> bf16 (packed or row-major) ----------------
template<bool PACK>
__global__ void reduce_h(const float* __restrict__ part, const float* __restrict__ bias,
                         unsigned short* __restrict__ out, int S) {
  int g4 = blockIdx.x * 256 + threadIdx.x;     // < 256*3968
  int row = g4 / 3968;
  int c   = (g4 - row * 3968) * 4;
  size_t off = (size_t)row * NHID + c;
  float4 s = *reinterpret_cast<const float4*>(part + off);
  for (int k = 1; k < S; ++k) {
    float4 p = *reinterpret_cast<const float4*>(part + (size_t)k * 256 * NHID + off);
    s.x += p.x; s.y += p.y; s.z += p.z; s.w += p.w;
  }
  float4 b = *reinterpret_cast<const float4*>(bias + c);
  s.x += b.x; s.y += b.y; s.z += b.z; s.w += b.w;
  us4 o;
  o[0] = f2bf(s.x > 0.f ? s.x : 0.f);
  o[1] = f2bf(s.y > 0.f ? s.y : 0.f);
  o[2] = f2bf(s.z > 0.f ? s.z : 0.f);
  o[3] = f2bf(s.w > 0.f ? s.w : 0.f);
  if (PACK) *reinterpret_cast<us4*>(out + pk_idx(row, c)) = o;
  else      *reinterpret_cast<us4*>(out + off) = o;
}

// ---------------- fold Wout [15872][992] -> Wv [15872][32] ----------------
__global__ void wv_fold(const float* __restrict__ Wout, float* __restrict__ Wv) {
  int g = blockIdx.x * 256 + threadIdx.x;
  int k = g >> 5, c = g & 31;
  const float* row = Wout + (size_t)k * 992;
  float s = 0.f;
#pragma unroll
  for (int o = 0; o < 32; ++o) {
    if (o == c) continue;
    int i = c < o ? c : o;
    int j = c < o ? o : c;
    int p = 31 * i - (i * (i - 1)) / 2 + (j - i - 1);
    s += row[2 * p + (c > o ? 1 : 0)];
  }
  Wv[g] = s;
}

// ---------------- votes partial = h2 @ Wv, K-split 32 ----------------
__global__ void votes_partial(const unsigned short* __restrict__ h2,
                              const float* __restrict__ Wv,
                              float* __restrict__ part) {
  int bm = blockIdx.x >> 5;
  int ks = blockIdx.x & 31;
  int r  = bm * 8 + (threadIdx.x >> 5);
  int c  = threadIdx.x & 31;
  const unsigned short* hrow = h2 + (size_t)r * NHID + ks * 496;
  const float* wp = Wv + (size_t)(ks * 496) * 32 + c;
  float s = 0.f;
  for (int k0 = 0; k0 < 496; k0 += 8) {
    short8 hv = *reinterpret_cast<const short8*>(hrow + k0);
#pragma unroll
    for (int j = 0; j < 8; ++j)
      s += bf2f((unsigned short)hv[j]) * wp[(size_t)(k0 + j) * 32];
  }
  part[(size_t)(ks * 256 + r) * 32 + c] = s;
}

// ---------------- reduce votes + bias-fold ----------------
__global__ void votes_reduce(const float* __restrict__ part,
                             const float* __restrict__ bout,
                             float* __restrict__ out) {
  int g = blockIdx.x * 256 + threadIdx.x;
  int c = g & 31;
  float s = 0.f;
#pragma unroll
  for (int ks = 0; ks < 32; ++ks) s += part[(size_t)ks * 8192 + g];
  float bv = 0.f;
#pragma unroll
  for (int o = 0; o < 32; ++o) {
    if (o == c) continue;
    int i = c < o ? c : o;
    int j = c < o ? o : c;
    int p = 31 * i - (i * (i - 1)) / 2 + (j - i - 1);
    bv += bout[2 * p + (c > o ? 1 : 0)];
  }
  out[g] = s + bv;
}

extern "C" void kernel_launch(void* const* d_in, const int* in_sizes, int n_in,
                              void* d_out, int out_size, void* d_ws, size_t ws_size,
                              hipStream_t stream) {
  const float* x    = (const float*)d_in[0];
  const float* W1   = (const float*)d_in[1];
  const float* b1   = (const float*)d_in[2];
  const float* W2   = (const float*)d_in[3];
  const float* b2   = (const float*)d_in[4];
  const float* Wout = (const float*)d_in[5];
  const float* bout = (const float*)d_in[6];
  float* out = (float*)d_out;

  char* ws = (char*)d_ws;
  unsigned short* xpk  = (unsigned short*)(ws);                     // 262144
  unsigned short* h1pk = (unsigned short*)(ws + 262144);            // 8126464
  unsigned short* h2   = (unsigned short*)(ws + 8388608);           // 8126464
  float*          Wv   = (float*)(ws + 16515072);                   // 2031616
  float*          part = (float*)(ws + 18546688);                   // 1048576
  float*         part2 = (float*)(ws + 19595264);                   // up to 4*256*NHID*4

  const size_t PART1 = (size_t)256 * NHID * 4;
  const bool split = ws_size >= 19595264ull + 4 * PART1;

  hipLaunchKernelGGL(cvt_x_pack, dim3(64), dim3(256), 0, stream, x, xpk);
  if (split) {
    // GEMM1: K=512 split 2 ways -> partials -> packed h1
    hipLaunchKernelGGL((gemm_v11<1, false>), dim3(124, 2), dim3(512), 0, stream,
                       xpk, 256, W1, (const float*)nullptr,
                       (unsigned short*)nullptr, part2);
    hipLaunchKernelGGL((reduce_h<true>), dim3(3968), dim3(256), 0, stream,
                       part2, b1, h1pk, 2);
    // GEMM2: K=15872 split 4 ways, 496 WGs = 2/CU with disjoint B
    hipLaunchKernelGGL((gemm_v11<1, true>), dim3(496), dim3(512), 0, stream,
                       h1pk, 3968, W2, (const float*)nullptr,
                       (unsigned short*)nullptr, part2);
    hipLaunchKernelGGL((reduce_h<false>), dim3(3968), dim3(256), 0, stream,
                       part2, b2, h2, 4);
  } else {
    hipLaunchKernelGGL((gemm_v11<0, false>), dim3(124, 1), dim3(512), 0, stream,
                       xpk, 512, W1, b1, h1pk, (float*)nullptr);
    hipLaunchKernelGGL((gemm_v11<2, false>), dim3(124, 1), dim3(512), 0, stream,
                       h1pk, NHID, W2, b2, h2, (float*)nullptr);
  }
  hipLaunchKernelGGL(wv_fold,       dim3(1984), dim3(256), 0, stream, Wout, Wv);
  hipLaunchKernelGGL(votes_partial, dim3(1024), dim3(256), 0, stream, h2, Wv, part);
  hipLaunchKernelGGL(votes_reduce,  dim3(32),   dim3(256), 0, stream, part, bout, out);
}

// Round 12
// 393.967 us; speedup vs baseline: 7.1444x; 7.1444x over previous
//
#include <hip/hip_runtime.h>
#include <hip/hip_bf16.h>

using short8 = __attribute__((ext_vector_type(8))) short;
using f32x16 = __attribute__((ext_vector_type(16))) float;
using us4    = __attribute__((ext_vector_type(4))) unsigned short;

#define NHID 15872

__device__ __forceinline__ unsigned short f2bf(float f) {
  unsigned u = __builtin_bit_cast(unsigned, f);
  u += 0x7fff + ((u >> 16) & 1);          // RNE
  return (unsigned short)(u >> 16);
}
__device__ __forceinline__ short f2bf_hw(float f) {
  __hip_bfloat16 h = __float2bfloat16(f);
  return __builtin_bit_cast(short, h);
}
__device__ __forceinline__ float bf2f(unsigned short h) {
  return __builtin_bit_cast(float, ((unsigned)h) << 16);
}

// async global->LDS, 16B/lane. LDS dest = wave-uniform base + lane*16.
__device__ __forceinline__ void gload16(const void* g, void* l) {
  __builtin_amdgcn_global_load_lds(
      (const __attribute__((address_space(1))) unsigned int*)g,
      (__attribute__((address_space(3))) unsigned int*)l, 16, 0, 0);
}

// packed-A layout: (row,k) -> (k>>4)*4096 + (row + 256*((k>>3)&1))*8 + (k&7)
__device__ __forceinline__ size_t pk_idx(int row, int col) {
  return (size_t)(col >> 4) * 4096 +
         (size_t)(row + 256 * ((col >> 3) & 1)) * 8 + (col & 7);
}

// ---------------- kernel 0: x fp32 -> packed bf16 ----------------
__global__ void cvt_x_pack(const float* __restrict__ x, unsigned short* __restrict__ xpk) {
  int g = blockIdx.x * 256 + threadIdx.x;       // 16384 chunks of 8
  int row = g >> 6, k0 = (g & 63) * 8;
  const float* p = x + (size_t)row * 512 + k0;
  float4 a = *reinterpret_cast<const float4*>(p);
  float4 b = *reinterpret_cast<const float4*>(p + 4);
  us4 o0, o1;
  o0[0] = f2bf(a.x); o0[1] = f2bf(a.y); o0[2] = f2bf(a.z); o0[3] = f2bf(a.w);
  o1[0] = f2bf(b.x); o1[1] = f2bf(b.y); o1[2] = f2bf(b.z); o1[3] = f2bf(b.w);
  unsigned short* d = xpk + pk_idx(row, k0);
  *reinterpret_cast<us4*>(d)     = o0;
  *reinterpret_cast<us4*>(d + 4) = o1;
}

// ---------------- main GEMM v12 ----------------
// BM=256, BN=128, BK=32. 512 thr = 8 waves (4m x 2n): wave = 64 rows x 64 cols,
// acc = 4 x f32x16 (64 AGPR). B-only LDS ring-3 (48 KB) -> 2 WG/CU with
// DISJOINT B. A loaded per-tile global->reg from packed image (L2-hot),
// SINGLE buffer (no ping-pong: fits 128-reg unified budget, no spill).
// Order per tile: WAITV(2) / barrier / LOADA(t) / STAGEB(t+2) / COMPUTE(t).
// Compiler's A-wait (vmcnt(2)) leaves the B prefetch in flight.

#define WAITV(N) asm volatile("s_waitcnt vmcnt(" #N ")" ::: "memory")

// B tile 32k x 128col fp32: wave w stages rows w*4..w*4+3 (2 instrs x 2 rows)
#define STAGEB(BUF, T) do { \
    gload16(bsrc + (size_t)(T) * 32 * NHID,       &Blds[BUF][(w * 4 + 0) * 128]); \
    gload16(bsrc + ((size_t)(T) * 32 + 2) * NHID, &Blds[BUF][(w * 4 + 2) * 128]); \
  } while (0)

#define LOADA(T) do { \
    const unsigned short* ap_ = asrc + (size_t)(T) * 8192; \
    rA[0] = *reinterpret_cast<const short8*>(ap_); \
    rA[1] = *reinterpret_cast<const short8*>(ap_ + 4096); \
    rA[2] = *reinterpret_cast<const short8*>(ap_ + 256); \
    rA[3] = *reinterpret_cast<const short8*>(ap_ + 4096 + 256); \
  } while (0)

#define COMPUTE(BC) do { \
    const float* bb_ = &Blds[BC][0]; \
    _Pragma("unroll") \
    for (int ks_ = 0; ks_ < 2; ++ks_) { \
      short8 bfr_[2]; \
      _Pragma("unroll") \
      for (int nb_ = 0; nb_ < 2; ++nb_) { \
        float tf_[8]; \
        _Pragma("unroll") \
        for (int jj_ = 0; jj_ < 8; ++jj_) \
          tf_[jj_] = bb_[(ks_ * 16 + hi * 8 + jj_) * 128 + wn * 64 + nb_ * 32 + l31]; \
        _Pragma("unroll") \
        for (int jj_ = 0; jj_ < 8; ++jj_) bfr_[nb_][jj_] = f2bf_hw(tf_[jj_]); \
      } \
      acc[0] = __builtin_amdgcn_mfma_f32_32x32x16_bf16(rA[ks_],     bfr_[0], acc[0], 0, 0, 0); \
      acc[1] = __builtin_amdgcn_mfma_f32_32x32x16_bf16(rA[ks_],     bfr_[1], acc[1], 0, 0, 0); \
      acc[2] = __builtin_amdgcn_mfma_f32_32x32x16_bf16(rA[2 + ks_], bfr_[0], acc[2], 0, 0, 0); \
      acc[3] = __builtin_amdgcn_mfma_f32_32x32x16_bf16(rA[2 + ks_], bfr_[1], acc[3], 0, 0, 0); \
    } \
  } while (0)

template<int OUTMODE, bool SWZ>
__global__ __launch_bounds__(512, 4)
void gemm_v12(const unsigned short* __restrict__ Apk, int KC,
              const float* __restrict__ B, const float* __restrict__ bias,
              unsigned short* __restrict__ Cf, float* __restrict__ Cp)
{
  __shared__ float Blds[3][32 * 128];   // 48 KB ring-3

  int nidx, ks0;
  if (SWZ) {
    int b = blockIdx.x;                  // 496 = 62 groups x 8 xcd-slots
    int xcd = b & 7;
    ks0  = xcd >> 1;                     // 2 XCDs per k-chunk (A slice 2MB -> L2)
    nidx = (b >> 3) * 2 + (xcd & 1);     // 0..123
  } else {
    nidx = blockIdx.x; ks0 = blockIdx.y;
  }
  const int n0   = nidx * 128;
  const int k0   = ks0 * KC;
  const int tid  = threadIdx.x;
  const int w    = tid >> 6;
  const int lane = tid & 63;
  const int l31  = lane & 31;
  const int hi   = lane >> 5;
  const int wm   = w >> 1;     // rows wm*64..+63
  const int wn   = w & 1;      // cols wn*64..+63

  f32x16 acc[4] = {};   // [rb*2+nb], lives in AGPR
  short8 rA[4];

  // B stage src: row = k0 + t*32 + w*4 + {0,2} + hi, col = n0 + l31*4
  const float* bsrc = B + (size_t)(k0 + w * 4 + hi) * NHID + n0 + l31 * 4;
  // A frag src (packed): + (t*2+ks)*4096 + rb*256 shorts
  const unsigned short* asrc = Apk + (size_t)(k0 >> 4) * 4096 +
                               (size_t)(wm * 64 + l31 + 256 * hi) * 8;

  const int NT = KC >> 5;   // >= 8, even, in all uses

  STAGEB(0, 0);
  STAGEB(1, 1);

  int bc = 0;
  for (int t = 0; t < NT; ++t) {
    if (t + 1 < NT) { WAITV(2); } else { WAITV(0); }
    __builtin_amdgcn_sched_barrier(0);
    __builtin_amdgcn_s_barrier();            // all waves' stage(t) landed
    LOADA(t);                                 // issued BEFORE next stage
    if (t + 2 < NT) { int sb_ = bc >= 1 ? bc - 1 : 2; STAGEB(sb_, t + 2); }
    COMPUTE(bc);
    bc = bc == 2 ? 0 : bc + 1;
  }

  // epilogue: verified mapping col=base+l31, row=(reg&3)+8*(reg>>2)+4*hi
#pragma unroll
  for (int rb = 0; rb < 2; ++rb) {
#pragma unroll
    for (int nb = 0; nb < 2; ++nb) {
      int col = n0 + wn * 64 + nb * 32 + l31;
      float bv = (OUTMODE != 1) ? bias[col] : 0.f;
#pragma unroll
      for (int reg = 0; reg < 16; ++reg) {
        int row = wm * 64 + rb * 32 + (reg & 3) + 8 * (reg >> 2) + 4 * hi;
        float v = acc[rb * 2 + nb][reg];
        if (OUTMODE == 0) {
          v += bv; v = v > 0.f ? v : 0.f;
          Cf[pk_idx(row, col)] = f2bf(v);
        } else if (OUTMODE == 1) {
          Cp[(size_t)ks0 * 256 * NHID + (size_t)row * NHID + col] = v;
        } else {
          v += bv; v = v > 0.f ? v : 0.f;
          Cf[(size_t)row * NHID + col] = f2bf(v);
        }
      }
    }
  }
}

// ---------------- reduce partials: out = relu(sum + bias) -> bf16 (packed or row-major) ----------------
template<bool PACK>
__global__ void reduce_h(const float* __restrict__ part, const float* __restrict__ bias,
                         unsigned short* __restrict__ out, int S) {
  int g4 = blockIdx.x * 256 + threadIdx.x;     // < 256*3968
  int row = g4 / 3968;
  int c   = (g4 - row * 3968) * 4;
  size_t off = (size_t)row * NHID + c;
  float4 s = *reinterpret_cast<const float4*>(part + off);
  for (int k = 1; k < S; ++k) {
    float4 p = *reinterpret_cast<const float4*>(part + (size_t)k * 256 * NHID + off);
    s.x += p.x; s.y += p.y; s.z += p.z; s.w += p.w;
  }
  float4 b = *reinterpret_cast<const float4*>(bias + c);
  s.x += b.x; s.y += b.y; s.z += b.z; s.w += b.w;
  us4 o;
  o[0] = f2bf(s.x > 0.f ? s.x : 0.f);
  o[1] = f2bf(s.y > 0.f ? s.y : 0.f);
  o[2] = f2bf(s.z > 0.f ? s.z : 0.f);
  o[3] = f2bf(s.w > 0.f ? s.w : 0.f);
  if (PACK) *reinterpret_cast<us4*>(out + pk_idx(row, c)) = o;
  else      *reinterpret_cast<us4*>(out + off) = o;
}

// ---------------- fold Wout [15872][992] -> Wv [15872][32] ----------------
__global__ void wv_fold(const float* __restrict__ Wout, float* __restrict__ Wv) {
  int g = blockIdx.x * 256 + threadIdx.x;
  int k = g >> 5, c = g & 31;
  const float* row = Wout + (size_t)k * 992;
  float s = 0.f;
#pragma unroll
  for (int o = 0; o < 32; ++o) {
    if (o == c) continue;
    int i = c < o ? c : o;
    int j = c < o ? o : c;
    int p = 31 * i - (i * (i - 1)) / 2 + (j - i - 1);
    s += row[2 * p + (c > o ? 1 : 0)];
  }
  Wv[g] = s;
}

// ---------------- votes partial = h2 @ Wv, K-split 32 ----------------
__global__ void votes_partial(const unsigned short* __restrict__ h2,
                              const float* __restrict__ Wv,
                              float* __restrict__ part) {
  int bm = blockIdx.x >> 5;
  int ks = blockIdx.x & 31;
  int r  = bm * 8 + (threadIdx.x >> 5);
  int c  = threadIdx.x & 31;
  const unsigned short* hrow = h2 + (size_t)r * NHID + ks * 496;
  const float* wp = Wv + (size_t)(ks * 496) * 32 + c;
  float s = 0.f;
  for (int k0 = 0; k0 < 496; k0 += 8) {
    short8 hv = *reinterpret_cast<const short8*>(hrow + k0);
#pragma unroll
    for (int j = 0; j < 8; ++j)
      s += bf2f((unsigned short)hv[j]) * wp[(size_t)(k0 + j) * 32];
  }
  part[(size_t)(ks * 256 + r) * 32 + c] = s;
}

// ---------------- reduce votes + bias-fold ----------------
__global__ void votes_reduce(const float* __restrict__ part,
                             const float* __restrict__ bout,
                             float* __restrict__ out) {
  int g = blockIdx.x * 256 + threadIdx.x;
  int c = g & 31;
  float s = 0.f;
#pragma unroll
  for (int ks = 0; ks < 32; ++ks) s += part[(size_t)ks * 8192 + g];
  float bv = 0.f;
#pragma unroll
  for (int o = 0; o < 32; ++o) {
    if (o == c) continue;
    int i = c < o ? c : o;
    int j = c < o ? o : c;
    int p = 31 * i - (i * (i - 1)) / 2 + (j - i - 1);
    bv += bout[2 * p + (c > o ? 1 : 0)];
  }
  out[g] = s + bv;
}

extern "C" void kernel_launch(void* const* d_in, const int* in_sizes, int n_in,
                              void* d_out, int out_size, void* d_ws, size_t ws_size,
                              hipStream_t stream) {
  const float* x    = (const float*)d_in[0];
  const float* W1   = (const float*)d_in[1];
  const float* b1   = (const float*)d_in[2];
  const float* W2   = (const float*)d_in[3];
  const float* b2   = (const float*)d_in[4];
  const float* Wout = (const float*)d_in[5];
  const float* bout = (const float*)d_in[6];
  float* out = (float*)d_out;

  char* ws = (char*)d_ws;
  unsigned short* xpk  = (unsigned short*)(ws);                     // 262144
  unsigned short* h1pk = (unsigned short*)(ws + 262144);            // 8126464
  unsigned short* h2   = (unsigned short*)(ws + 8388608);           // 8126464
  float*          Wv   = (float*)(ws + 16515072);                   // 2031616
  float*          part = (float*)(ws + 18546688);                   // 1048576
  float*         part2 = (float*)(ws + 19595264);                   // up to 4*256*NHID*4

  const size_t PART1 = (size_t)256 * NHID * 4;
  const bool split = ws_size >= 19595264ull + 4 * PART1;

  hipLaunchKernelGGL(cvt_x_pack, dim3(64), dim3(256), 0, stream, x, xpk);
  if (split) {
    // GEMM1: K=512 split 2 ways -> partials -> packed h1
    hipLaunchKernelGGL((gemm_v12<1, false>), dim3(124, 2), dim3(512), 0, stream,
                       xpk, 256, W1, (const float*)nullptr,
                       (unsigned short*)nullptr, part2);
    hipLaunchKernelGGL((reduce_h<true>), dim3(3968), dim3(256), 0, stream,
                       part2, b1, h1pk, 2);
    // GEMM2: K=15872 split 4 ways, 496 WGs = 2/CU with disjoint B
    hipLaunchKernelGGL((gemm_v12<1, true>), dim3(496), dim3(512), 0, stream,
                       h1pk, 3968, W2, (const float*)nullptr,
                       (unsigned short*)nullptr, part2);
    hipLaunchKernelGGL((reduce_h<false>), dim3(3968), dim3(256), 0, stream,
                       part2, b2, h2, 4);
  } else {
    hipLaunchKernelGGL((gemm_v12<0, false>), dim3(124, 1), dim3(512), 0, stream,
                       xpk, 512, W1, b1, h1pk, (float*)nullptr);
    hipLaunchKernelGGL((gemm_v12<2, false>), dim3(124, 1), dim3(512), 0, stream,
                       h1pk, NHID, W2, b2, h2, (float*)nullptr);
  }
  hipLaunchKernelGGL(wv_fold,       dim3(1984), dim3(256), 0, stream, Wout, Wv);
  hipLaunchKernelGGL(votes_partial, dim3(1024), dim3(256), 0, stream, h2, Wv, part);
  hipLaunchKernelGGL(votes_reduce,  dim3(32),   dim3(256), 0, stream, part, bout, out);
}